// Round 8
// baseline (261.414 us; speedup 1.0000x reference)
//
#include <hip/hip_runtime.h>

namespace {

constexpr int W_RES = 320, H_RES = 240, BS = 4, VD = 128, NS = 256;
constexpr int NPIX = W_RES * H_RES;
constexpr int K_SEG = 4;
constexpr float DENS_SCALE = 100.0f / 256.0f / 255.0f;  // u8 units -> ds
constexpr float TAU = 5e-4f;   // early-exit transmittance (per segment, local)
constexpr long long VOX = (long long)VD * VD * VD;  // 2,097,152

constexpr size_t VOL_BYTES = (size_t)BS * VOX * 8;               // 67,108,864
constexpr size_t SEGA_BYTES = (size_t)K_SEG * BS * NPIX * 16;    // 19,660,800
// segT after segA

// Transpose (B,4,D,H,W) fp32 -> (B,D,H,W) of uint2 entries:
// entry[x] = (u8x4 voxel[x], u8x4 voxel[x+1]), voxel[128] == 0 pad.
__global__ void transpose_k(const float* __restrict__ vol, uint4* __restrict__ out) {
    long long tid = (long long)blockIdx.x * blockDim.x + threadIdx.x;
    const long long npair = (long long)BS * VOX / 2;
    if (tid >= npair) return;
    int b = (int)(tid / (VOX / 2));
    long long r = (tid - (long long)b * (VOX / 2)) * 2;  // even entry index
    int x = (int)(r & (VD - 1));
    bool last = (x == VD - 2);
    const float* vb = vol + (long long)b * 4 * VOX + r;
    float2 R = *(const float2*)(vb);
    float2 G = *(const float2*)(vb + VOX);
    float2 Bl = *(const float2*)(vb + 2 * VOX);
    float2 Dn = *(const float2*)(vb + 3 * VOX);
    float R2 = last ? 0.0f : vb[2];
    float G2 = last ? 0.0f : vb[VOX + 2];
    float B2 = last ? 0.0f : vb[2 * VOX + 2];
    float D2 = last ? 0.0f : vb[3 * VOX + 2];
    auto pk = [](float r_, float g_, float bl_, float d_) -> unsigned {
        unsigned ur = (unsigned)(r_ * 255.0f + 0.5f);
        unsigned ug = (unsigned)(g_ * 255.0f + 0.5f);
        unsigned ub = (unsigned)(bl_ * 255.0f + 0.5f);
        unsigned ud = (unsigned)(d_ * 255.0f + 0.5f);
        return ur | (ug << 8) | (ub << 16) | (ud << 24);
    };
    unsigned p0 = pk(R.x, G.x, Bl.x, Dn.x);
    unsigned p1 = pk(R.y, G.y, Bl.y, Dn.y);
    unsigned p2 = pk(R2, G2, B2, D2);
    uint4 o;
    o.x = p0; o.y = p1;
    o.z = p1; o.w = p2;
    out[tid] = o;
}

struct St {
    uint2 p[4];    // corner-pairs: (z0,y0) (z0,y1) (z1,y0) (z1,y1)
    float wzy[4];
    float wlo, whi;
};

struct Coord {
    int x0, y0, z0;
    float fx, fy, fz;
    bool fast;
};

__device__ __forceinline__ Coord mkc(float ix, float iy, float iz) {
    Coord c;
    float f;
    f = floorf(ix); c.fx = ix - f; c.x0 = (int)f;
    f = floorf(iy); c.fy = iy - f; c.y0 = (int)f;
    f = floorf(iz); c.fz = iz - f; c.z0 = (int)f;
    c.fast = ((unsigned)c.x0 < 128u) & ((unsigned)c.y0 < 127u) & ((unsigned)c.z0 < 127u);
    return c;
}

__device__ __forceinline__ void stage_fast(const uint2* __restrict__ vb,
                                           const Coord& c, St& st) {
    const uint2* r0 = vb + ((c.z0 * VD + c.y0) * VD + c.x0);
    const uint2* r1 = r0 + VD * VD;
    st.p[0] = r0[0];
    st.p[1] = r0[VD];
    st.p[2] = r1[0];
    st.p[3] = r1[VD];
    st.wlo = 1.0f - c.fx;
    st.whi = c.fx;
    float wy0 = 1.0f - c.fy, wy1 = c.fy;
    float wz0 = 1.0f - c.fz, wz1 = c.fz;
    st.wzy[0] = wz0 * wy0; st.wzy[1] = wz0 * wy1;
    st.wzy[2] = wz1 * wy0; st.wzy[3] = wz1 * wy1;
}

__device__ __forceinline__ void stage_safe(const uint2* __restrict__ vb,
                                           const Coord& c, St& st) {
    int x0 = c.x0, y0 = c.y0, z0 = c.z0;
    bool in01x = ((unsigned)x0 < 128u);
    bool ism1 = (x0 == -1);
    st.wlo = in01x ? (1.0f - c.fx) : (ism1 ? c.fx : 0.0f);
    st.whi = in01x ? c.fx : 0.0f;
    int bx = min(max(x0, 0), 127);

    float my0 = ((unsigned)y0 < 128u) ? 1.0f : 0.0f;
    float my1 = ((unsigned)(y0 + 1) < 128u) ? 1.0f : 0.0f;
    float mz0 = ((unsigned)z0 < 128u) ? 1.0f : 0.0f;
    float mz1 = ((unsigned)(z0 + 1) < 128u) ? 1.0f : 0.0f;
    int yc0 = min(max(y0, 0), 127), yc1 = min(max(y0 + 1, 0), 127);
    int zc0 = min(max(z0, 0), 127), zc1 = min(max(z0 + 1, 0), 127);

    st.p[0] = vb[(zc0 * VD + yc0) * VD + bx];
    st.p[1] = vb[(zc0 * VD + yc1) * VD + bx];
    st.p[2] = vb[(zc1 * VD + yc0) * VD + bx];
    st.p[3] = vb[(zc1 * VD + yc1) * VD + bx];

    float wy0 = (1.0f - c.fy) * my0, wy1 = c.fy * my1;
    float wz0 = (1.0f - c.fz) * mz0, wz1 = c.fz * mz1;
    st.wzy[0] = wz0 * wy0; st.wzy[1] = wz0 * wy1;
    st.wzy[2] = wz1 * wy0; st.wzy[3] = wz1 * wy1;
}

__device__ __forceinline__ void consume(const St& st, float& T, float& wsum,
                                        float& aR, float& aG, float& aB) {
    float ar = 0, ag = 0, ab = 0, ad = 0;
#pragma unroll
    for (int i = 0; i < 4; ++i) {
        unsigned lo = st.p[i].x, hi = st.p[i].y;
        float wl = st.wzy[i] * st.wlo;
        float wh = st.wzy[i] * st.whi;
        ar = fmaf(wl, (float)(lo & 255u), ar);
        ag = fmaf(wl, (float)((lo >> 8) & 255u), ag);
        ab = fmaf(wl, (float)((lo >> 16) & 255u), ab);
        ad = fmaf(wl, (float)(lo >> 24), ad);
        ar = fmaf(wh, (float)(hi & 255u), ar);
        ag = fmaf(wh, (float)((hi >> 8) & 255u), ag);
        ab = fmaf(wh, (float)((hi >> 16) & 255u), ab);
        ad = fmaf(wh, (float)(hi >> 24), ad);
    }
    float dsv = ad * DENS_SCALE;
    T *= (1.0f - dsv);
    float wgt = dsv * T;
    wsum += wgt;
    aR = fmaf(wgt, ar, aR);
    aG = fmaf(wgt, ag, aG);
    aB = fmaf(wgt, ab, aB);
}

// Each block: one 16x16 pixel tile x one s-segment (k). Each wave: 16x4 strip.
// Writes local segment composite (R,G,B,wsum) and local T to ws buffers.
__global__ void __launch_bounds__(256) raycast_k(const uint2* __restrict__ vol,
                                                 const float* __restrict__ tfm,
                                                 float4* __restrict__ segA,
                                                 float* __restrict__ segT) {
    int lane = threadIdx.x & 63;
    int wave = threadIdx.x >> 6;
    int bx = blockIdx.x;               // 0..19
    int by = blockIdx.y;               // 0..14
    int k = blockIdx.z & (K_SEG - 1);  // segment index
    int b = blockIdx.z >> 2;           // batch
    int x = bx * 16 + (lane & 15);
    int y = by * 16 + wave * 4 + (lane >> 4);

    float X = -1.0f + 2.0f * x / (float)(W_RES - 1);
    float Y = -1.0f + 2.0f * y / (float)(H_RES - 1);
    const float dZ = 2.0f / (float)(NS - 1);

    const float* M = tfm + b * 16;
    float bxc = M[0] * X + M[1] * Y + M[3];
    float byc = M[4] * X + M[5] * Y + M[7];
    float bzc = M[8] * X + M[9] * Y + M[11];
    float bwc = M[12] * X + M[13] * Y + M[15];
    float m02 = M[2], m12 = M[6], m22 = M[10], m32 = M[14];

    const uint2* vb = vol + (long long)b * VOX;

    // Ray-box clip (exact when w row trivial; guarded for generality).
    bool w1 = (fabsf(bwc - 1.0f) < 1e-6f) && (fabsf(m32) < 1e-6f);
    float lo = 0.0f, hi = (float)(NS - 1);
    if (w1) {
        const float LIM = 1.0078125f + 1e-5f;
        auto clipAxis = [&](float bb, float mm) {
            float A = bb - mm;  // g(s) = A + B*s
            float Bq = mm * dZ;
            if (fabsf(Bq) < 1e-9f) {
                if (fabsf(A) > LIM) { lo = 1.0f; hi = 0.0f; }
            } else {
                float s1 = (-LIM - A) / Bq, s2 = (LIM - A) / Bq;
                lo = fmaxf(lo, fminf(s1, s2));
                hi = fminf(hi, fmaxf(s1, s2));
            }
        };
        clipAxis(bxc, m02);
        clipAxis(byc, m12);
        clipAxis(bzc, m22);
    }
    int s_start = max(0, (int)ceilf(lo - 1e-3f));
    int s_end = min(NS - 1, (int)floorf(hi + 1e-3f));

    // wave-common range over VALID lanes only
    int rs = (s_start <= s_end) ? s_start : 0x7fffffff;
    int re = (s_start <= s_end) ? s_end : -0x7fffffff;
#pragma unroll
    for (int off = 1; off < 64; off <<= 1) {
        rs = min(rs, __shfl_xor(rs, off));
        re = max(re, __shfl_xor(re, off));
    }

    float T = 1.0f, wsum = 0.0f, aR = 0.0f, aG = 0.0f, aB = 0.0f;

    int segLo = 1, segHi = 0;
    if (rs <= re) {
        int L = re - rs + 1;
        int slen = (L + K_SEG - 1) / K_SEG;
        segLo = rs + k * slen;
        segHi = min(re, segLo + slen - 1);
    }

    // Per-lane sample end CLAMPED TO THIS SEGMENT (round-7 bug: used s_end,
    // double-counting samples segHi+1, segHi+2 into the next segment too).
    int se = min(s_end, segHi);

    auto coords = [&](int s, float& ix, float& iy, float& iz) {
        float Z = fmaf((float)s, dZ, -1.0f);
        float gx = fmaf(m02, Z, bxc);
        float gy = fmaf(m12, Z, byc);
        float gz = fmaf(m22, Z, bzc);
        if (!w1) {
            float iw = 1.0f / fmaf(m32, Z, bwc);
            gx *= iw; gy *= iw; gz *= iw;
        }
        ix = fmaf(gx, 64.0f, 63.5f);
        iy = fmaf(gy, 64.0f, 63.5f);
        iz = fmaf(gz, 64.0f, 63.5f);
    };

    St S0, S1, S2;
    for (int s = segLo; s <= segHi; s += 3) {
        bool alive = (T >= TAU);
        bool g0 = (s >= s_start) & (s <= se) & alive;
        bool g1 = (s + 1 >= s_start) & (s + 1 <= se) & alive;
        bool g2 = (s + 2 >= s_start) & (s + 2 <= se) & alive;
        Coord c0, c1, c2;
        float ix, iy, iz;
        if (g0) { coords(s, ix, iy, iz); c0 = mkc(ix, iy, iz); }
        if (g1) { coords(s + 1, ix, iy, iz); c1 = mkc(ix, iy, iz); }
        if (g2) { coords(s + 2, ix, iy, iz); c2 = mkc(ix, iy, iz); }
        bool fastAll = __all((g0 ? c0.fast : true) & (g1 ? c1.fast : true) &
                             (g2 ? c2.fast : true));
        if (fastAll) {
            if (g0) stage_fast(vb, c0, S0);
            if (g1) stage_fast(vb, c1, S1);
            if (g2) stage_fast(vb, c2, S2);
        } else {
            if (g0) stage_safe(vb, c0, S0);
            if (g1) stage_safe(vb, c1, S1);
            if (g2) stage_safe(vb, c2, S2);
        }
        __builtin_amdgcn_sched_barrier(0);  // keep loads hoisted above consumes
        if (g0) consume(S0, T, wsum, aR, aG, aB);
        if (g1 & (T >= TAU)) consume(S1, T, wsum, aR, aG, aB);
        if (g2 & (T >= TAU)) consume(S2, T, wsum, aR, aG, aB);
        if (!__any((T >= TAU) & (s + 3 <= segHi))) break;
    }

    long long sidx = ((long long)k * BS + b) * NPIX + y * W_RES + x;
    segA[sidx] = make_float4(aR, aG, aB, wsum);
    segT[sidx] = T;
}

// Composite K_SEG segments per pixel (associative over-compositing).
__global__ void combine_k(const float4* __restrict__ segA,
                          const float* __restrict__ segT,
                          float* __restrict__ out) {
    int tid = blockIdx.x * blockDim.x + threadIdx.x;
    if (tid >= BS * NPIX) return;  // tid = b*NPIX + pix
    float aR = 0, aG = 0, aB = 0, ws = 0, Tg = 1.0f;
#pragma unroll
    for (int k = 0; k < K_SEG; ++k) {
        long long idx = (long long)k * BS * NPIX + tid;
        float4 a = segA[idx];
        float t = segT[idx];
        aR = fmaf(Tg, a.x, aR);
        aG = fmaf(Tg, a.y, aG);
        aB = fmaf(Tg, a.z, aB);
        ws = fmaf(Tg, a.w, ws);
        Tg *= t;
    }
    float scale = (1.0f - Tg) / (ws + 1e-6f) * (1.0f / 255.0f);
    int b = tid / NPIX;
    int pix = tid - b * NPIX;
    float* ob = out + (long long)b * 3 * NPIX;
    ob[pix] = aR * scale;
    ob[pix + NPIX] = aG * scale;
    ob[pix + 2 * NPIX] = aB * scale;
}

}  // namespace

extern "C" void kernel_launch(void* const* d_in, const int* in_sizes, int n_in,
                              void* d_out, int out_size, void* d_ws, size_t ws_size,
                              hipStream_t stream) {
    const float* vol = (const float*)d_in[0];  // (4,4,128,128,128) fp32
    const float* tfm = (const float*)d_in[1];  // (4,4,4) fp32
    float* out = (float*)d_out;                // (4,3,240,320) fp32

    unsigned char* ws = (unsigned char*)d_ws;
    uint4* v8 = (uint4*)ws;                                   // 67.1 MB volume
    float4* segA = (float4*)(ws + VOL_BYTES);                 // 19.7 MB
    float* segT = (float*)(ws + VOL_BYTES + SEGA_BYTES);      // 4.9 MB
    (void)ws_size; (void)in_sizes; (void)n_in; (void)out_size;

    const long long npair = (long long)BS * VOX / 2;  // 4,194,304
    transpose_k<<<(int)((npair + 255) / 256), 256, 0, stream>>>(vol, v8);

    dim3 grid(W_RES / 16, H_RES / 16, BS * K_SEG);  // 20 x 15 x 16 = 4800 blocks
    raycast_k<<<grid, 256, 0, stream>>>((const uint2*)v8, tfm, segA, segT);

    combine_k<<<(BS * NPIX + 255) / 256, 256, 0, stream>>>(segA, segT, out);
}